// Round 1
// baseline (6326.093 us; speedup 1.0000x reference)
//
#include <hip/hip_runtime.h>
#include <math.h>

namespace {

constexpr int kN = 1024;   // sequence length
constexpr int kD = 128;    // head dim
constexpr int kBH = 64;    // B*H
constexpr int TI = 64;     // query rows per block
constexpr int TJ = 64;     // key cols per tile
constexpr int NTH = 256;   // threads per block
constexpr int STR = 36;    // LDS row stride (floats) for 32-wide D-chunk tiles

constexpr float INV2SD = 0.04419417382415922f;  // 1/(2*sqrt(128))
constexpr float INVSD  = 0.08838834764831843f;  // 1/sqrt(128)
constexpr float TWOA   = 2.0f + 1e-5f;
constexpr float PIF    = 3.14159265358979323846f;

__device__ __forceinline__ float sigm(float x) {
  return 1.0f / (1.0f + __expf(-x));
}

// acc[a][b] += dot4(A[row ty4+a][kk..kk+3], B[row tx4+b][kk..kk+3])
__device__ __forceinline__ void gram4x4(float (&acc)[4][4],
                                        const float* __restrict__ At,
                                        const float* __restrict__ Bt,
                                        int kk) {
  float4 A[4], Bv[4];
#pragma unroll
  for (int a = 0; a < 4; ++a) A[a] = *(const float4*)(At + a * STR + kk);
#pragma unroll
  for (int b = 0; b < 4; ++b) Bv[b] = *(const float4*)(Bt + b * STR + kk);
#pragma unroll
  for (int a = 0; a < 4; ++a)
#pragma unroll
    for (int b = 0; b < 4; ++b)
      acc[a][b] += A[a].x * Bv[b].x + A[a].y * Bv[b].y +
                   A[a].z * Bv[b].z + A[a].w * Bv[b].w;
}

__global__ __launch_bounds__(NTH, 2)
void cpka_main(const float* __restrict__ q, const float* __restrict__ k,
               const float* __restrict__ v, float* __restrict__ outp,
               float* __restrict__ attnp) {
  const int bh = blockIdx.x >> 4;         // 16 i-tiles per bh
  const int i0 = (blockIdx.x & 15) * TI;
  const int t = threadIdx.x;
  const int tx = t & 15, ty = t >> 4;

  __shared__ float s_qn2[kN], s_kn2[kN], s_rk[kN], s_sks[kN];
  __shared__ float s_rq[TI], s_sqs[TI], s_inv[TI];
  __shared__ float s_stage[6 * 64 * STR];  // 6 tiles; also aliased pre+vals

  const float* qb = q + (size_t)bh * kN * kD;
  const float* kb = k + (size_t)bh * kN * kD;
  const float* vb = v + (size_t)bh * kN * kD;
  float* attb = attnp + (size_t)bh * kN * kN;
  float* outb = outp + (size_t)bh * kN * kD;

  // ---- per-row stats for all rows of this bh ----
  for (int r = t; r < kN; r += NTH) {
    const float4* qr = (const float4*)(qb + r * kD);
    const float4* kr = (const float4*)(kb + r * kD);
    float qs = 0.f, ks = 0.f;
#pragma unroll 8
    for (int c = 0; c < kD / 4; ++c) {
      float4 a = qr[c];
      qs += a.x * a.x + a.y * a.y + a.z * a.z + a.w * a.w;
      float4 b2 = kr[c];
      ks += b2.x * b2.x + b2.y * b2.y + b2.z * b2.z + b2.w * b2.w;
    }
    s_qn2[r] = qs;
    s_kn2[r] = ks;
    float rk_ = 1.0f / sqrtf(ks);
    s_rk[r] = rk_;
    float ss = 0.f;
#pragma unroll 8
    for (int c = 0; c < kD / 4; ++c) {
      float4 b2 = kr[c];
      ss += sigm(b2.x * rk_) + sigm(b2.y * rk_) +
            sigm(b2.z * rk_) + sigm(b2.w * rk_);
    }
    s_sks[r] = ss;
  }
  __syncthreads();
  if (t < TI) {
    int i = i0 + t;
    float rq_ = 1.0f / sqrtf(s_qn2[i]);
    s_rq[t] = rq_;
    const float4* qr = (const float4*)(qb + i * kD);
    float ss = 0.f;
#pragma unroll 8
    for (int c = 0; c < kD / 4; ++c) {
      float4 a = qr[c];
      ss += sigm(a.x * rq_) + sigm(a.y * rq_) +
            sigm(a.z * rq_) + sigm(a.w * rq_);
    }
    s_sqs[t] = ss;
  }
  __syncthreads();

  float oacc[4][8];
#pragma unroll
  for (int a = 0; a < 4; ++a)
#pragma unroll
    for (int u = 0; u < 8; ++u) oacc[a][u] = 0.f;
  float rowss[4] = {0.f, 0.f, 0.f, 0.f};

  for (int jt = 0; jt < kN / TJ; ++jt) {
    const int j0 = jt * TJ;
    float aqk[4][4] = {}, akq[4][4] = {}, as1[4][4] = {};

    for (int dc = 0; dc < 4; ++dc) {
      const int d0 = dc * 32;
      // stage 6 tiles of [64][32] f32 (stride STR)
#pragma unroll
      for (int u = 0; u < 2; ++u) {
        int fid = t * 2 + u;        // 0..511
        int row = fid >> 3;         // 0..63
        int cf = (fid & 7) * 4;     // float col 0..28
        float4 qi = *(const float4*)(qb + (i0 + row) * kD + d0 + cf);
        float4 kj = *(const float4*)(kb + (j0 + row) * kD + d0 + cf);
        float4 ki = *(const float4*)(kb + (i0 + row) * kD + d0 + cf);
        float4 qj = *(const float4*)(qb + (j0 + row) * kD + d0 + cf);
        *(float4*)&s_stage[(0 * 64 + row) * STR + cf] = qi;
        *(float4*)&s_stage[(1 * 64 + row) * STR + cf] = kj;
        *(float4*)&s_stage[(2 * 64 + row) * STR + cf] = ki;
        *(float4*)&s_stage[(3 * 64 + row) * STR + cf] = qj;
        float rq_ = s_rq[row];
        float rk_ = s_rk[j0 + row];
        float4 sq4, sk4;
        sq4.x = sigm(qi.x * rq_); sq4.y = sigm(qi.y * rq_);
        sq4.z = sigm(qi.z * rq_); sq4.w = sigm(qi.w * rq_);
        sk4.x = sigm(kj.x * rk_); sk4.y = sigm(kj.y * rk_);
        sk4.z = sigm(kj.z * rk_); sk4.w = sigm(kj.w * rk_);
        *(float4*)&s_stage[(4 * 64 + row) * STR + cf] = sq4;
        *(float4*)&s_stage[(5 * 64 + row) * STR + cf] = sk4;
      }
      __syncthreads();
      const float* At0 = &s_stage[(0 * 64 + ty * 4) * STR];
      const float* Bt0 = &s_stage[(1 * 64 + tx * 4) * STR];
      const float* At1 = &s_stage[(2 * 64 + ty * 4) * STR];
      const float* Bt1 = &s_stage[(3 * 64 + tx * 4) * STR];
      const float* At2 = &s_stage[(4 * 64 + ty * 4) * STR];
      const float* Bt2 = &s_stage[(5 * 64 + tx * 4) * STR];
#pragma unroll
      for (int kk = 0; kk < 32; kk += 4) {
        gram4x4(aqk, At0, Bt0, kk);
        gram4x4(akq, At1, Bt1, kk);
        gram4x4(as1, At2, Bt2, kk);
      }
      __syncthreads();
    }

    // ---- elementwise epilogue for this 64x64 tile ----
    float pre[4][4];
#pragma unroll
    for (int a = 0; a < 4; ++a) {
      const int i = i0 + ty * 4 + a;
      const float qn2i = s_qn2[i], kn2i = s_kn2[i];
      const float rqi = s_rq[ty * 4 + a], sqsi = s_sqs[ty * 4 + a];
#pragma unroll
      for (int b = 0; b < 4; ++b) {
        const int j = j0 + tx * 4 + b;
        const float qn2j = s_qn2[j], kn2j = s_kn2[j];
        const float rkj = s_rk[j], sksj = s_sks[j];
        // SE term: index-crossed distance ||k_i - q_j|| (torch broadcast quirk)
        float se = -sqrtf(fmaxf(kn2i + qn2j - 2.0f * akq[a][b], 0.0f)) * INV2SD;
        float cs = aqk[a][b] * rqi * rkj;
        float pres = PIF * sqrtf(fmaxf(TWOA - 2.0f * cs, 0.0f));
        float sn = __sinf(pres);
        float per = -2.0f * sn * sn * INVSD;
        float A = as1[a][b];
        float Bc = (float)kD - sqsi - sksj + A;
        float p = A * __expf(se) + Bc * __expf(per) + (qn2i + kn2j) * INV2SD;
        pre[a][b] = p;
        rowss[a] += p * p;
      }
      float4 pw = make_float4(pre[a][0], pre[a][1], pre[a][2], pre[a][3]);
      *(float4*)&attb[(size_t)i * kN + j0 + tx * 4] = pw;  // un-normalized
    }

    // ---- accumulate out partials: pre-tile (LDS) x vals-tile (LDS) ----
    float* s_pre = s_stage;             // [64][65]
    float* s_vals = s_stage + 64 * 65;  // [64][128]
#pragma unroll
    for (int a = 0; a < 4; ++a)
#pragma unroll
      for (int b = 0; b < 4; ++b)
        s_pre[(ty * 4 + a) * 65 + tx * 4 + b] = pre[a][b];
#pragma unroll
    for (int u = 0; u < 8; ++u) {
      int fid = u * NTH + t;      // 0..2047
      int row = fid >> 5;         // 0..63
      int cf = (fid & 31) * 4;    // 0..124
      *(float4*)&s_vals[row * kD + cf] =
          *(const float4*)(vb + (j0 + row) * kD + cf);
    }
    __syncthreads();
#pragma unroll 8
    for (int jj = 0; jj < TJ; ++jj) {
      float pr[4];
#pragma unroll
      for (int a = 0; a < 4; ++a) pr[a] = s_pre[(ty * 4 + a) * 65 + jj];
      const float* vrow = &s_vals[jj * kD + tx * 8];
#pragma unroll
      for (int u = 0; u < 8; ++u) {
        float vv = vrow[u];
#pragma unroll
        for (int a = 0; a < 4; ++a) oacc[a][u] += pr[a] * vv;
      }
    }
    __syncthreads();
  }  // jt

  // ---- row norm: reduce across the 16 tx lanes (consecutive lanes) ----
#pragma unroll
  for (int a = 0; a < 4; ++a) {
#pragma unroll
    for (int m = 1; m < 16; m <<= 1) rowss[a] += __shfl_xor(rowss[a], m);
  }
  float invn[4];
#pragma unroll
  for (int a = 0; a < 4; ++a)
    invn[a] = 1.0f / fmaxf(sqrtf(rowss[a]), 1e-12f);

  if (tx == 0) {
#pragma unroll
    for (int a = 0; a < 4; ++a) s_inv[ty * 4 + a] = invn[a];
  }

  // ---- write out = (pre @ vals) * invn ----
#pragma unroll
  for (int a = 0; a < 4; ++a) {
    float* orow = &outb[(size_t)(i0 + ty * 4 + a) * kD + tx * 8];
    float4 w0, w1;
    w0.x = oacc[a][0] * invn[a]; w0.y = oacc[a][1] * invn[a];
    w0.z = oacc[a][2] * invn[a]; w0.w = oacc[a][3] * invn[a];
    w1.x = oacc[a][4] * invn[a]; w1.y = oacc[a][5] * invn[a];
    w1.z = oacc[a][6] * invn[a]; w1.w = oacc[a][7] * invn[a];
    *(float4*)&orow[0] = w0;
    *(float4*)&orow[4] = w1;
  }
  __syncthreads();

  // ---- rescale this block's attn rows in place (L2-hot) ----
  for (int it = 0; it < TI * (kN / 4) / NTH; ++it) {
    int idx = it * NTH + t;
    int row = idx >> 8;           // kN/4 = 256 float4 per row
    int cf = (idx & 255) * 4;
    float inv = s_inv[row];
    float4* p = (float4*)&attb[(size_t)(i0 + row) * kN + cf];
    float4 x = *p;
    x.x *= inv; x.y *= inv; x.z *= inv; x.w *= inv;
    *p = x;
  }
}

}  // namespace

extern "C" void kernel_launch(void* const* d_in, const int* in_sizes, int n_in,
                              void* d_out, int out_size, void* d_ws, size_t ws_size,
                              hipStream_t stream) {
  (void)in_sizes; (void)n_in; (void)out_size; (void)d_ws; (void)ws_size;
  const float* q = (const float*)d_in[0];
  const float* k = (const float*)d_in[1];
  const float* v = (const float*)d_in[2];
  float* outp = (float*)d_out;
  float* attnp = outp + (size_t)kBH * kN * kD;
  dim3 grid(kBH * (kN / TI));
  cpka_main<<<grid, NTH, 0, stream>>>(q, k, v, outp, attnp);
}

// Round 5
// 995.842 us; speedup vs baseline: 6.3525x; 6.3525x over previous
//
#include <hip/hip_runtime.h>
#include <math.h>

namespace {

constexpr int kN = 1024;
constexpr int kD = 128;
constexpr int kBH = 64;
constexpr int IT = 32;     // i rows per block
constexpr int JT = 64;     // j cols per tile
constexpr int NTH = 256;   // 4 waves
constexpr int SI = 136;    // i-side LDS row stride (bf16 elems)
constexpr int SJ = 136;    // j-side LDS row stride
constexpr int SP = 1032;   // pre-buffer row stride (bf16 elems)

constexpr float INV2SD = 0.04419417382415922f;  // 1/(2*sqrt(128))
constexpr float INVSD  = 0.08838834764831843f;  // 1/sqrt(128)
constexpr float TWOA   = 2.0f + 1e-5f;
constexpr float PIF    = 3.14159265358979323846f;

typedef __attribute__((ext_vector_type(8))) short s16x8;   // 8 bf16 (4 VGPR)
typedef __attribute__((ext_vector_type(4))) short s16x4;   // 4 bf16 (2 VGPR)
typedef __attribute__((ext_vector_type(4))) float f32x4;   // mfma C/D + ext-vector f32

__device__ __forceinline__ unsigned short f2bf(float f) {
  unsigned u = __float_as_uint(f);
  u += 0x7fffu + ((u >> 16) & 1u);   // RNE
  return (unsigned short)(u >> 16);
}
__device__ __forceinline__ float bf2f(unsigned short b) {
  return __uint_as_float(((unsigned)b) << 16);
}
__device__ __forceinline__ float sigm(float x) { return 1.0f / (1.0f + __expf(-x)); }

__global__ __launch_bounds__(NTH, 1)
void cpka(const float* __restrict__ q, const float* __restrict__ k,
          const float* __restrict__ v, float* __restrict__ outp,
          float* __restrict__ attnp) {
  // XCD-chunked swizzle: 2048 blocks = 8 XCDs x 256; same-bh blocks share an XCD's L2.
  const int hw = blockIdx.x;
  const int lg = (hw & 7) * 256 + (hw >> 3);
  const int bh = lg >> 5;
  const int i0 = (lg & 31) * IT;
  const int t = threadIdx.x;
  const int lane = t & 63;
  const int w = t >> 6;                 // wave 0..3
  const int l15 = lane & 15, l4 = lane >> 4;

  __shared__ unsigned short Qhi[IT * SI];   // q-hat (unit) i-rows, bf16
  __shared__ unsigned short Kii[IT * SI];   // raw K i-rows
  __shared__ unsigned short Sqi[IT * SI];   // sigmoid(q-hat) i-rows
  __shared__ unsigned short Khj[JT * SJ];   // k-hat j-rows
  __shared__ unsigned short Qjj[JT * SJ];   // raw Q j-rows
  __shared__ unsigned short Skj[JT * SJ];   // sigmoid(k-hat) j-rows
  __shared__ unsigned short Vt[kD * 64];    // V^T tile [d][j], XOR-swizzled 8-elem blocks
  __shared__ unsigned short Pre[IT * SP];   // un-normalized pre, bf16
  __shared__ float s_qn2i[IT], s_kn2i[IT], s_sqsi[IT];
  __shared__ float s_qn2j[JT], s_kn2j[JT], s_sksj[JT];
  __shared__ float s_part[4][IT];
  __shared__ float s_invn[IT];

  const float* qb = q + (size_t)bh * kN * kD;
  const float* kb = k + (size_t)bh * kN * kD;
  const float* vb = v + (size_t)bh * kN * kD;
  float* attb = attnp + (size_t)bh * kN * kN;
  float* outb = outp + (size_t)bh * kN * kD;

  // ---------------- i-side staging (once) ----------------
  {
    const bool isQ = (t < 128);
    const int tt = isQ ? t : t - 128;
    const int row = tt >> 2, qt = tt & 3;      // 4 threads per row, 32 f32 each
    const float* src = (isQ ? qb : kb) + (size_t)(i0 + row) * kD + qt * 32;
    float4 vv[8];
    float ss = 0.f;
#pragma unroll
    for (int c = 0; c < 8; ++c) {
      vv[c] = ((const float4*)src)[c];
      ss += vv[c].x * vv[c].x + vv[c].y * vv[c].y + vv[c].z * vv[c].z + vv[c].w * vv[c].w;
    }
    ss += __shfl_xor(ss, 1);
    ss += __shfl_xor(ss, 2);
    if (isQ) {
      const float rn = rsqrtf(ss);
      float sg = 0.f;
#pragma unroll
      for (int c = 0; c < 8; ++c) {
        float x0 = vv[c].x * rn, x1 = vv[c].y * rn, x2 = vv[c].z * rn, x3 = vv[c].w * rn;
        s16x4 hb; hb[0] = f2bf(x0); hb[1] = f2bf(x1); hb[2] = f2bf(x2); hb[3] = f2bf(x3);
        *(s16x4*)&Qhi[row * SI + qt * 32 + c * 4] = hb;
        float g0 = sigm(x0), g1 = sigm(x1), g2 = sigm(x2), g3 = sigm(x3);
        sg += g0 + g1 + g2 + g3;
        s16x4 sb; sb[0] = f2bf(g0); sb[1] = f2bf(g1); sb[2] = f2bf(g2); sb[3] = f2bf(g3);
        *(s16x4*)&Sqi[row * SI + qt * 32 + c * 4] = sb;
      }
      sg += __shfl_xor(sg, 1);
      sg += __shfl_xor(sg, 2);
      if (qt == 0) { s_qn2i[row] = ss; s_sqsi[row] = sg; }
    } else {
#pragma unroll
      for (int c = 0; c < 8; ++c) {
        s16x4 hb;
        hb[0] = f2bf(vv[c].x); hb[1] = f2bf(vv[c].y);
        hb[2] = f2bf(vv[c].z); hb[3] = f2bf(vv[c].w);
        *(s16x4*)&Kii[row * SI + qt * 32 + c * 4] = hb;
      }
      if (qt == 0) s_kn2i[row] = ss;
    }
  }

  f32x4 oacc[2][2];
#pragma unroll
  for (int m = 0; m < 2; ++m)
#pragma unroll
    for (int np = 0; np < 2; ++np) oacc[m][np] = (f32x4){0.f, 0.f, 0.f, 0.f};
  float rowss[2] = {0.f, 0.f};

  for (int jt = 0; jt < kN / JT; ++jt) {
    const int j0 = jt * JT;
    __syncthreads();   // previous PV readers done before restaging

    // ---------------- j-side + V staging ----------------
    if (t < 128) {          // K rows: khat, sigm(khat), kn2, sks
      const int row = t >> 1, half = t & 1;   // 2 threads per row, 64 f32 each
      const float* src = kb + (size_t)(j0 + row) * kD + half * 64;
      float4 vv[16];
      float ss = 0.f;
#pragma unroll
      for (int c = 0; c < 16; ++c) {
        vv[c] = ((const float4*)src)[c];
        ss += vv[c].x * vv[c].x + vv[c].y * vv[c].y + vv[c].z * vv[c].z + vv[c].w * vv[c].w;
      }
      ss += __shfl_xor(ss, 1);
      const float rn = rsqrtf(ss);
      float sg = 0.f;
#pragma unroll
      for (int c = 0; c < 16; ++c) {
        float x0 = vv[c].x * rn, x1 = vv[c].y * rn, x2 = vv[c].z * rn, x3 = vv[c].w * rn;
        s16x4 hb; hb[0] = f2bf(x0); hb[1] = f2bf(x1); hb[2] = f2bf(x2); hb[3] = f2bf(x3);
        *(s16x4*)&Khj[row * SJ + half * 64 + c * 4] = hb;
        float g0 = sigm(x0), g1 = sigm(x1), g2 = sigm(x2), g3 = sigm(x3);
        sg += g0 + g1 + g2 + g3;
        s16x4 sb; sb[0] = f2bf(g0); sb[1] = f2bf(g1); sb[2] = f2bf(g2); sb[3] = f2bf(g3);
        *(s16x4*)&Skj[row * SJ + half * 64 + c * 4] = sb;
      }
      sg += __shfl_xor(sg, 1);
      if (half == 0) { s_kn2j[row] = ss; s_sksj[row] = sg; }
    } else {                // Q rows: raw bf16 + qn2
      const int tt = t - 128;
      const int row = tt >> 1, half = tt & 1;
      const float* src = qb + (size_t)(j0 + row) * kD + half * 64;
      float ss = 0.f;
#pragma unroll
      for (int c = 0; c < 16; ++c) {
        float4 vv = ((const float4*)src)[c];
        ss += vv.x * vv.x + vv.y * vv.y + vv.z * vv.z + vv.w * vv.w;
        s16x4 hb;
        hb[0] = f2bf(vv.x); hb[1] = f2bf(vv.y); hb[2] = f2bf(vv.z); hb[3] = f2bf(vv.w);
        *(s16x4*)&Qjj[row * SJ + half * 64 + c * 4] = hb;
      }
      ss += __shfl_xor(ss, 1);
      if (half == 0) s_qn2j[row] = ss;
    }
    {  // V tile -> transposed [d][j] with XOR-swizzled 8-elem j-blocks
      const int row = t >> 2, qt = t & 3;     // row = j-local, qt = d-quarter
      const float* src = vb + (size_t)(j0 + row) * kD + qt * 32;
      const int jlow = row & 7, jblk = row >> 3;
#pragma unroll
      for (int c = 0; c < 8; ++c) {
        float4 vv = ((const float4*)src)[c];
        const int d0 = qt * 32 + c * 4;
        float f0 = vv.x, f1 = vv.y, f2 = vv.z, f3 = vv.w;
        Vt[(d0 + 0) * 64 + (((jblk ^ ((d0 + 0) & 7))) << 3) + jlow] = f2bf(f0);
        Vt[(d0 + 1) * 64 + (((jblk ^ ((d0 + 1) & 7))) << 3) + jlow] = f2bf(f1);
        Vt[(d0 + 2) * 64 + (((jblk ^ ((d0 + 2) & 7))) << 3) + jlow] = f2bf(f2);
        Vt[(d0 + 3) * 64 + (((jblk ^ ((d0 + 3) & 7))) << 3) + jlow] = f2bf(f3);
      }
    }
    __syncthreads();

    // ---------------- grams (P^T orientation: a = j-side, b = i-side) ----------------
    f32x4 acos[2], ase[2], as1[2];
#pragma unroll
    for (int ni = 0; ni < 2; ++ni) {
      acos[ni] = (f32x4){0.f, 0.f, 0.f, 0.f};
      ase[ni]  = (f32x4){0.f, 0.f, 0.f, 0.f};
      as1[ni]  = (f32x4){0.f, 0.f, 0.f, 0.f};
    }
    const int arow = (w * 16 + l15) * SJ + l4 * 8;
    const int brow = l15 * SI + l4 * 8;
#pragma unroll
    for (int ks = 0; ks < 4; ++ks) {
      const int ao = arow + ks * 32;
      const s16x8 aC = *(const s16x8*)&Khj[ao];
      const s16x8 aS = *(const s16x8*)&Qjj[ao];
      const s16x8 aP = *(const s16x8*)&Skj[ao];
#pragma unroll
      for (int ni = 0; ni < 2; ++ni) {
        const int bo = brow + ni * 16 * SI + ks * 32;
        acos[ni] = __builtin_amdgcn_mfma_f32_16x16x32_bf16(aC, *(const s16x8*)&Qhi[bo], acos[ni], 0, 0, 0);
        ase[ni]  = __builtin_amdgcn_mfma_f32_16x16x32_bf16(aS, *(const s16x8*)&Kii[bo], ase[ni], 0, 0, 0);
        as1[ni]  = __builtin_amdgcn_mfma_f32_16x16x32_bf16(aP, *(const s16x8*)&Sqi[bo], as1[ni], 0, 0, 0);
      }
    }

    // ---------------- epilogue: pre, row-sumsq, pack to Pre ----------------
#pragma unroll
    for (int ni = 0; ni < 2; ++ni) {
      const int iloc = ni * 16 + l15;
      const float kn2i = s_kn2i[iloc], qn2i = s_qn2i[iloc], sqsi = s_sqsi[iloc];
      s16x4 pk;
      float rs = 0.f;
#pragma unroll
      for (int r = 0; r < 4; ++r) {
        const int jloc = w * 16 + l4 * 4 + r;
        const float kq = ase[ni][r];    // q_j . k_i (index-crossed SE term)
        const float cs = acos[ni][r];   // qhat_i . khat_j
        const float s1 = as1[ni][r];    // sig(qhat_i) . sig(khat_j)
        const float se = -sqrtf(fmaxf(kn2i + s_qn2j[jloc] - 2.0f * kq, 0.f)) * INV2SD;
        const float pres = PIF * sqrtf(fmaxf(TWOA - 2.0f * cs, 0.f));
        const float sn = __sinf(pres);
        const float per = -2.0f * sn * sn * INVSD;
        const float Bc = 128.0f - sqsi - s_sksj[jloc] + s1;
        const float p = s1 * __expf(se) + Bc * __expf(per)
                        + (qn2i + s_kn2j[jloc]) * INV2SD;
        rs += p * p;
        pk[r] = (short)f2bf(p);
      }
      rowss[ni] += rs;
      *(s16x4*)&Pre[iloc * SP + j0 + w * 16 + l4 * 4] = pk;
    }
    __syncthreads();

    // ---------------- PV: out += P_tile @ V_tile ----------------
#pragma unroll
    for (int ks2 = 0; ks2 < 2; ++ks2) {
      const int jb = j0 + ks2 * 32 + l4 * 8;
      const s16x8 A0 = *(const s16x8*)&Pre[l15 * SP + jb];
      const s16x8 A1 = *(const s16x8*)&Pre[(16 + l15) * SP + jb];
#pragma unroll
      for (int np = 0; np < 2; ++np) {
        const int d = (w * 2 + np) * 16 + l15;   // this lane's output d-column
        // B[k = l4*8+e][n = l15] = V[j = ks2*32 + l4*8 + e][d]; plain b128 read
        const s16x8 B = *(const s16x8*)&Vt[d * 64 + (((ks2 * 4 + l4) ^ (d & 7)) << 3)];
        oacc[0][np] = __builtin_amdgcn_mfma_f32_16x16x32_bf16(A0, B, oacc[0][np], 0, 0, 0);
        oacc[1][np] = __builtin_amdgcn_mfma_f32_16x16x32_bf16(A1, B, oacc[1][np], 0, 0, 0);
      }
    }
  }  // jt

  // ---------------- row L2 norm ----------------
#pragma unroll
  for (int ni = 0; ni < 2; ++ni) {
    float rsv = rowss[ni];
    rsv += __shfl_xor(rsv, 16);
    rsv += __shfl_xor(rsv, 32);
    if (l4 == 0) s_part[w][ni * 16 + l15] = rsv;
  }
  __syncthreads();
  if (t < IT) {
    const float ssum = s_part[0][t] + s_part[1][t] + s_part[2][t] + s_part[3][t];
    s_invn[t] = 1.0f / fmaxf(sqrtf(ssum), 1e-12f);
  }
  __syncthreads();

  // ---------------- out = (pre @ vals) * invn ----------------
#pragma unroll
  for (int m = 0; m < 2; ++m)
#pragma unroll
    for (int np = 0; np < 2; ++np)
#pragma unroll
      for (int r = 0; r < 4; ++r) {
        const int iloc = m * 16 + l4 * 4 + r;
        const int d = w * 32 + np * 16 + l15;
        outb[(size_t)(i0 + iloc) * kD + d] = oacc[m][np][r] * s_invn[iloc];
      }

  // ---------------- attn = Pre * invn, written once, coalesced, nontemporal ----------------
#pragma unroll 4
  for (int u = 0; u < 16; ++u) {
    const int c = u * NTH + t;
    const int row = c >> 7;
    const int col = (c & 127) * 8;
    const s16x8 hv = *(const s16x8*)&Pre[row * SP + col];
    const float inv = s_invn[row];
    f32x4 w0, w1;
    w0[0] = bf2f((unsigned short)hv[0]) * inv;
    w0[1] = bf2f((unsigned short)hv[1]) * inv;
    w0[2] = bf2f((unsigned short)hv[2]) * inv;
    w0[3] = bf2f((unsigned short)hv[3]) * inv;
    w1[0] = bf2f((unsigned short)hv[4]) * inv;
    w1[1] = bf2f((unsigned short)hv[5]) * inv;
    w1[2] = bf2f((unsigned short)hv[6]) * inv;
    w1[3] = bf2f((unsigned short)hv[7]) * inv;
    float* dst = attb + (size_t)(i0 + row) * kN + col;
    __builtin_nontemporal_store(w0, (f32x4*)dst);
    __builtin_nontemporal_store(w1, (f32x4*)(dst + 4));
  }
}

}  // namespace

extern "C" void kernel_launch(void* const* d_in, const int* in_sizes, int n_in,
                              void* d_out, int out_size, void* d_ws, size_t ws_size,
                              hipStream_t stream) {
  (void)in_sizes; (void)n_in; (void)out_size; (void)d_ws; (void)ws_size;
  const float* q = (const float*)d_in[0];
  const float* k = (const float*)d_in[1];
  const float* v = (const float*)d_in[2];
  float* outp = (float*)d_out;
  float* attnp = outp + (size_t)kBH * kN * kD;
  dim3 grid(kBH * (kN / IT));   // 2048 = 8 XCDs * 256
  cpka<<<grid, NTH, 0, stream>>>(q, k, v, outp, attnp);
}

// Round 6
// 528.104 us; speedup vs baseline: 11.9789x; 1.8857x over previous
//
#include <hip/hip_runtime.h>
#include <math.h>

namespace {

constexpr int kN = 1024;
constexpr int kD = 128;
constexpr int kBH = 64;
constexpr int IT = 64;     // i rows per block
constexpr int JT = 64;     // j cols per tile
constexpr int NTH = 512;   // 8 waves
constexpr int SI = 136;    // i-side LDS row stride (bf16 elems)
constexpr int SJ = 136;    // j-side LDS row stride
constexpr int SPT = 72;    // per-tile Pre stride (bf16 elems)

constexpr float INV2SD = 0.04419417382415922f;  // 1/(2*sqrt(128))
constexpr float INVSD  = 0.08838834764831843f;  // 1/sqrt(128)
constexpr float TWOA   = 2.0f + 1e-5f;
constexpr float PIF    = 3.14159265358979323846f;

typedef __attribute__((ext_vector_type(8))) short s16x8;
typedef __attribute__((ext_vector_type(4))) short s16x4;
typedef __attribute__((ext_vector_type(4))) float f32x4;

__device__ __forceinline__ unsigned short f2bf(float f) {
  unsigned u = __float_as_uint(f);
  u += 0x7fffu + ((u >> 16) & 1u);   // RNE
  return (unsigned short)(u >> 16);
}
__device__ __forceinline__ float bf2f(unsigned short b) {
  return __uint_as_float(((unsigned)b) << 16);
}
__device__ __forceinline__ float sigm(float x) { return 1.0f / (1.0f + __expf(-x)); }

// Vt swizzle: 8-elem j-block index for (d, jblk). Involution; spreads banks on
// writes (qt -> d>>4) AND reads (l15 -> d&7).
__device__ __forceinline__ int vswz(int jblk, int d) {
  return (jblk ^ (d & 7) ^ ((d >> 4) & 7)) << 3;
}

__global__ __launch_bounds__(NTH, 1)
void cpka(const float* __restrict__ q, const float* __restrict__ k,
          const float* __restrict__ v, float* __restrict__ outp,
          float* __restrict__ attnp) {
  // XCD-chunked swizzle: 1024 blocks = 8 XCDs x 128; same-bh blocks share an XCD L2.
  const int hw = blockIdx.x;
  const int lg = (hw & 7) * 128 + (hw >> 3);
  const int bh = lg >> 4;
  const int i0 = (lg & 15) * IT;
  const int t = threadIdx.x;
  const int lane = t & 63;
  const int w = t >> 6;                 // wave 0..7
  const int l15 = lane & 15, l4 = lane >> 4;
  const int wjf = w & 3;                // j-frag 0..3
  const int wip = w >> 2;               // i-frag pair 0..1

  __shared__ unsigned short Qhi[IT * SI];   // q-hat i-rows
  __shared__ unsigned short Kii[IT * SI];   // raw K i-rows
  __shared__ unsigned short Sqi[IT * SI];   // sigmoid(q-hat) i-rows
  __shared__ unsigned short Khj[JT * SJ];   // k-hat j-rows
  __shared__ unsigned short Qjj[JT * SJ];   // raw Q j-rows
  __shared__ unsigned short Skj[JT * SJ];   // sigmoid(k-hat) j-rows
  __shared__ unsigned short Vt[kD * 64];    // V^T tile [d][j], swizzled 8-elem blocks
  __shared__ unsigned short PreT[IT * SPT]; // per-tile unnormalized pre, bf16
  __shared__ float s_qn2i[IT], s_kn2i[IT], s_sqsi[IT];
  __shared__ float s_qn2j[JT], s_kn2j[JT], s_sksj[JT];
  __shared__ float s_part[4][IT];
  __shared__ float s_invn[IT];

  const float* qb = q + (size_t)bh * kN * kD;
  const float* kb = k + (size_t)bh * kN * kD;
  const float* vb = v + (size_t)bh * kN * kD;
  float* attb = attnp + (size_t)bh * kN * kN;
  float* outb = outp + (size_t)bh * kN * kD;

  // ---------------- i-side staging (once): 4 threads/row, 32 f32 each ----------------
  {
    const bool isQ = (t < 256);
    const int tt = isQ ? t : t - 256;
    const int row = tt >> 2, qt = tt & 3;
    const float* src = (isQ ? qb : kb) + (size_t)(i0 + row) * kD + qt * 32;
    float4 vv[8];
    float ss = 0.f;
#pragma unroll
    for (int c = 0; c < 8; ++c) {
      vv[c] = ((const float4*)src)[c];
      ss += vv[c].x * vv[c].x + vv[c].y * vv[c].y + vv[c].z * vv[c].z + vv[c].w * vv[c].w;
    }
    ss += __shfl_xor(ss, 1);
    ss += __shfl_xor(ss, 2);
    if (isQ) {
      const float rn = rsqrtf(ss);
      float sg = 0.f;
#pragma unroll
      for (int c = 0; c < 8; ++c) {
        float x0 = vv[c].x * rn, x1 = vv[c].y * rn, x2 = vv[c].z * rn, x3 = vv[c].w * rn;
        s16x4 hb; hb[0] = f2bf(x0); hb[1] = f2bf(x1); hb[2] = f2bf(x2); hb[3] = f2bf(x3);
        *(s16x4*)&Qhi[row * SI + qt * 32 + c * 4] = hb;
        float g0 = sigm(x0), g1 = sigm(x1), g2 = sigm(x2), g3 = sigm(x3);
        sg += g0 + g1 + g2 + g3;
        s16x4 sb; sb[0] = f2bf(g0); sb[1] = f2bf(g1); sb[2] = f2bf(g2); sb[3] = f2bf(g3);
        *(s16x4*)&Sqi[row * SI + qt * 32 + c * 4] = sb;
      }
      sg += __shfl_xor(sg, 1);
      sg += __shfl_xor(sg, 2);
      if (qt == 0) { s_qn2i[row] = ss; s_sqsi[row] = sg; }
    } else {
#pragma unroll
      for (int c = 0; c < 8; ++c) {
        s16x4 hb;
        hb[0] = f2bf(vv[c].x); hb[1] = f2bf(vv[c].y);
        hb[2] = f2bf(vv[c].z); hb[3] = f2bf(vv[c].w);
        *(s16x4*)&Kii[row * SI + qt * 32 + c * 4] = hb;
      }
      if (qt == 0) s_kn2i[row] = ss;
    }
  }

  f32x4 oacc[2][2];
#pragma unroll
  for (int m = 0; m < 2; ++m)
#pragma unroll
    for (int np = 0; np < 2; ++np) oacc[m][np] = (f32x4){0.f, 0.f, 0.f, 0.f};
  float rowss[2] = {0.f, 0.f};

  for (int jt = 0; jt < kN / JT; ++jt) {
    const int j0 = jt * JT;
    __syncthreads();   // prev tile's PV/attn readers done before restage

    // ---------------- j-side staging: 4 threads/row, 32 f32 each ----------------
    if (t < 256) {          // K rows: khat, sigm(khat), kn2, sks
      const int row = t >> 2, qt = t & 3;
      const float* src = kb + (size_t)(j0 + row) * kD + qt * 32;
      float4 vv[8];
      float ss = 0.f;
#pragma unroll
      for (int c = 0; c < 8; ++c) {
        vv[c] = ((const float4*)src)[c];
        ss += vv[c].x * vv[c].x + vv[c].y * vv[c].y + vv[c].z * vv[c].z + vv[c].w * vv[c].w;
      }
      ss += __shfl_xor(ss, 1);
      ss += __shfl_xor(ss, 2);
      const float rn = rsqrtf(ss);
      float sg = 0.f;
#pragma unroll
      for (int c = 0; c < 8; ++c) {
        float x0 = vv[c].x * rn, x1 = vv[c].y * rn, x2 = vv[c].z * rn, x3 = vv[c].w * rn;
        s16x4 hb; hb[0] = f2bf(x0); hb[1] = f2bf(x1); hb[2] = f2bf(x2); hb[3] = f2bf(x3);
        *(s16x4*)&Khj[row * SJ + qt * 32 + c * 4] = hb;
        float g0 = sigm(x0), g1 = sigm(x1), g2 = sigm(x2), g3 = sigm(x3);
        sg += g0 + g1 + g2 + g3;
        s16x4 sb; sb[0] = f2bf(g0); sb[1] = f2bf(g1); sb[2] = f2bf(g2); sb[3] = f2bf(g3);
        *(s16x4*)&Skj[row * SJ + qt * 32 + c * 4] = sb;
      }
      sg += __shfl_xor(sg, 1);
      sg += __shfl_xor(sg, 2);
      if (qt == 0) { s_kn2j[row] = ss; s_sksj[row] = sg; }
    } else {                // Q rows: raw bf16 + qn2
      const int tt = t - 256;
      const int row = tt >> 2, qt = tt & 3;
      const float* src = qb + (size_t)(j0 + row) * kD + qt * 32;
      float ss = 0.f;
#pragma unroll
      for (int c = 0; c < 8; ++c) {
        float4 vv = ((const float4*)src)[c];
        ss += vv.x * vv.x + vv.y * vv.y + vv.z * vv.z + vv.w * vv.w;
        s16x4 hb;
        hb[0] = f2bf(vv.x); hb[1] = f2bf(vv.y); hb[2] = f2bf(vv.z); hb[3] = f2bf(vv.w);
        *(s16x4*)&Qjj[row * SJ + qt * 32 + c * 4] = hb;
      }
      ss += __shfl_xor(ss, 1);
      ss += __shfl_xor(ss, 2);
      if (qt == 0) s_qn2j[row] = ss;
    }
    {  // V tile -> transposed [d][j], swizzled; 8 threads/row, 16 d each
      const int row = t >> 3, qt = t & 7;
      const float* src = vb + (size_t)(j0 + row) * kD + qt * 16;
      const int jblk = row >> 3, jlow = row & 7;
#pragma unroll
      for (int c = 0; c < 4; ++c) {
        float4 vv = ((const float4*)src)[c];
        const int d0 = qt * 16 + c * 4;
        Vt[(d0 + 0) * 64 + vswz(jblk, d0 + 0) + jlow] = f2bf(vv.x);
        Vt[(d0 + 1) * 64 + vswz(jblk, d0 + 1) + jlow] = f2bf(vv.y);
        Vt[(d0 + 2) * 64 + vswz(jblk, d0 + 2) + jlow] = f2bf(vv.z);
        Vt[(d0 + 3) * 64 + vswz(jblk, d0 + 3) + jlow] = f2bf(vv.w);
      }
    }
    __syncthreads();

    // ---------------- grams (P^T: a = j-side, b = i-side) ----------------
    f32x4 acos[2], ase[2], as1[2];
#pragma unroll
    for (int ni = 0; ni < 2; ++ni) {
      acos[ni] = (f32x4){0.f, 0.f, 0.f, 0.f};
      ase[ni]  = (f32x4){0.f, 0.f, 0.f, 0.f};
      as1[ni]  = (f32x4){0.f, 0.f, 0.f, 0.f};
    }
    const int arow = (wjf * 16 + l15) * SJ + l4 * 8;
    const int brow0 = (wip * 32 + l15) * SI + l4 * 8;
#pragma unroll
    for (int ks = 0; ks < 4; ++ks) {
      const int ao = arow + ks * 32;
      const s16x8 aC = *(const s16x8*)&Khj[ao];
      const s16x8 aS = *(const s16x8*)&Qjj[ao];
      const s16x8 aP = *(const s16x8*)&Skj[ao];
#pragma unroll
      for (int ni = 0; ni < 2; ++ni) {
        const int bo = brow0 + ni * 16 * SI + ks * 32;
        acos[ni] = __builtin_amdgcn_mfma_f32_16x16x32_bf16(aC, *(const s16x8*)&Qhi[bo], acos[ni], 0, 0, 0);
        ase[ni]  = __builtin_amdgcn_mfma_f32_16x16x32_bf16(aS, *(const s16x8*)&Kii[bo], ase[ni], 0, 0, 0);
        as1[ni]  = __builtin_amdgcn_mfma_f32_16x16x32_bf16(aP, *(const s16x8*)&Sqi[bo], as1[ni], 0, 0, 0);
      }
    }

    // ---------------- epilogue: pre, row-sumsq, pack to PreT ----------------
#pragma unroll
    for (int ni = 0; ni < 2; ++ni) {
      const int iloc = wip * 32 + ni * 16 + l15;
      const float kn2i = s_kn2i[iloc], qn2i = s_qn2i[iloc], sqsi = s_sqsi[iloc];
      s16x4 pk;
      float rs = 0.f;
#pragma unroll
      for (int r = 0; r < 4; ++r) {
        const int jloc = wjf * 16 + l4 * 4 + r;
        const float kq = ase[ni][r];    // q_j . k_i (index-crossed SE term)
        const float cs = acos[ni][r];   // qhat_i . khat_j
        const float s1 = as1[ni][r];    // sig(qhat_i) . sig(khat_j)
        const float se = -sqrtf(fmaxf(kn2i + s_qn2j[jloc] - 2.0f * kq, 0.f)) * INV2SD;
        const float pres = PIF * sqrtf(fmaxf(TWOA - 2.0f * cs, 0.f));
        const float sn = __sinf(pres);
        const float per = -2.0f * sn * sn * INVSD;
        const float Bc = 128.0f - sqsi - s_sksj[jloc] + s1;
        const float p = s1 * __expf(se) + Bc * __expf(per)
                        + (qn2i + s_kn2j[jloc]) * INV2SD;
        rs += p * p;
        pk[r] = (short)f2bf(p);
      }
      rowss[ni] += rs;
      *(s16x4*)&PreT[iloc * SPT + wjf * 16 + l4 * 4] = pk;
    }
    __syncthreads();

    // ---------------- attn tile: unnormalized, coalesced ----------------
    {
      const int row = t >> 3, col = (t & 7) * 8;
      const s16x8 hv = *(const s16x8*)&PreT[row * SPT + col];
      f32x4 w0, w1;
      w0[0] = bf2f((unsigned short)hv[0]); w0[1] = bf2f((unsigned short)hv[1]);
      w0[2] = bf2f((unsigned short)hv[2]); w0[3] = bf2f((unsigned short)hv[3]);
      w1[0] = bf2f((unsigned short)hv[4]); w1[1] = bf2f((unsigned short)hv[5]);
      w1[2] = bf2f((unsigned short)hv[6]); w1[3] = bf2f((unsigned short)hv[7]);
      float* dst = attb + (size_t)(i0 + row) * kN + j0 + col;
      *(f32x4*)dst = w0;
      *(f32x4*)(dst + 4) = w1;
    }

    // ---------------- PV: out += P_tile @ V_tile ----------------
#pragma unroll
    for (int ks2 = 0; ks2 < 2; ++ks2) {
      const int jb = ks2 * 32 + l4 * 8;
      const s16x8 A0 = *(const s16x8*)&PreT[(wip * 32 + l15) * SPT + jb];
      const s16x8 A1 = *(const s16x8*)&PreT[(wip * 32 + 16 + l15) * SPT + jb];
#pragma unroll
      for (int np = 0; np < 2; ++np) {
        const int d = wjf * 32 + np * 16 + l15;   // this lane's output d-column
        const s16x8 B = *(const s16x8*)&Vt[d * 64 + vswz(ks2 * 4 + l4, d)];
        oacc[0][np] = __builtin_amdgcn_mfma_f32_16x16x32_bf16(A0, B, oacc[0][np], 0, 0, 0);
        oacc[1][np] = __builtin_amdgcn_mfma_f32_16x16x32_bf16(A1, B, oacc[1][np], 0, 0, 0);
      }
    }
  }  // jt

  // ---------------- row L2 norm (for out only; attn rescaled in pass 2) ----------------
#pragma unroll
  for (int ni = 0; ni < 2; ++ni) {
    float rsv = rowss[ni];
    rsv += __shfl_xor(rsv, 16);
    rsv += __shfl_xor(rsv, 32);
    if (l4 == 0) s_part[wjf][wip * 32 + ni * 16 + l15] = rsv;
  }
  __syncthreads();
  if (t < IT) {
    const float ssum = s_part[0][t] + s_part[1][t] + s_part[2][t] + s_part[3][t];
    s_invn[t] = 1.0f / fmaxf(sqrtf(ssum), 1e-12f);
  }
  __syncthreads();

  // ---------------- out = (pre @ vals) * invn ----------------
#pragma unroll
  for (int m = 0; m < 2; ++m)
#pragma unroll
    for (int np = 0; np < 2; ++np)
#pragma unroll
      for (int r = 0; r < 4; ++r) {
        const int iloc = wip * 32 + m * 16 + l4 * 4 + r;
        const int d = wjf * 32 + np * 16 + l15;
        outb[(size_t)(i0 + iloc) * kD + d] = oacc[m][np][r] * s_invn[iloc];
      }
}

// Pass 2: L2-normalize each attn row in place (recomputes denom from the
// unnormalized f32 row it reads anyway -- zero extra traffic, no ws needed).
__global__ __launch_bounds__(256, 8)
void cpka_rescale(float* __restrict__ attnp) {
  const size_t row = (size_t)blockIdx.x * 4 + (threadIdx.x >> 6);
  const int lane = threadIdx.x & 63;
  f32x4* rp = (f32x4*)(attnp + row * kN);
  f32x4 x[4];
  float ss = 0.f;
#pragma unroll
  for (int u = 0; u < 4; ++u) {
    x[u] = rp[lane + u * 64];
    ss += x[u][0] * x[u][0] + x[u][1] * x[u][1] + x[u][2] * x[u][2] + x[u][3] * x[u][3];
  }
#pragma unroll
  for (int m = 1; m < 64; m <<= 1) ss += __shfl_xor(ss, m);
  const float inv = 1.0f / fmaxf(sqrtf(ss), 1e-12f);
#pragma unroll
  for (int u = 0; u < 4; ++u) {
    f32x4 y = x[u];
    y[0] *= inv; y[1] *= inv; y[2] *= inv; y[3] *= inv;
    __builtin_nontemporal_store(y, &rp[lane + u * 64]);
  }
}

}  // namespace

extern "C" void kernel_launch(void* const* d_in, const int* in_sizes, int n_in,
                              void* d_out, int out_size, void* d_ws, size_t ws_size,
                              hipStream_t stream) {
  (void)in_sizes; (void)n_in; (void)out_size; (void)d_ws; (void)ws_size;
  const float* q = (const float*)d_in[0];
  const float* k = (const float*)d_in[1];
  const float* v = (const float*)d_in[2];
  float* outp = (float*)d_out;
  float* attnp = outp + (size_t)kBH * kN * kD;
  dim3 grid(kBH * (kN / IT));   // 1024 = 8 XCDs * 128
  cpka<<<grid, NTH, 0, stream>>>(q, k, v, outp, attnp);
  dim3 grid2(kBH * kN / 4);     // 4 rows per block
  cpka_rescale<<<grid2, 256, 0, stream>>>(attnp);
}

// Round 7
// 447.555 us; speedup vs baseline: 14.1348x; 1.1800x over previous
//
#include <hip/hip_runtime.h>
#include <math.h>

namespace {

constexpr int kN = 1024;
constexpr int kD = 128;
constexpr int kBH = 64;
constexpr int IT = 64;     // i rows per block
constexpr int JT = 64;     // j cols per tile
constexpr int NTH = 1024;  // 16 waves -> 4 waves/SIMD
constexpr int SI = 136;    // i-side LDS row stride (bf16 elems)
constexpr int SJ = 136;    // j-side LDS row stride
constexpr int SPT = 72;    // per-tile Pre stride (bf16 elems)

constexpr float INV2SD = 0.04419417382415922f;  // 1/(2*sqrt(128))
constexpr float INVSD  = 0.08838834764831843f;  // 1/sqrt(128)
constexpr float TWOA   = 2.0f + 1e-5f;

typedef __attribute__((ext_vector_type(8))) short s16x8;
typedef __attribute__((ext_vector_type(4))) short s16x4;
typedef __attribute__((ext_vector_type(4))) float f32x4;

__device__ __forceinline__ unsigned short f2bf(float f) {
  unsigned u = __float_as_uint(f);
  u += 0x7fffu + ((u >> 16) & 1u);   // RNE
  return (unsigned short)(u >> 16);
}
__device__ __forceinline__ float bf2f(unsigned short b) {
  return __uint_as_float(((unsigned)b) << 16);
}
__device__ __forceinline__ float sigm(float x) { return 1.0f / (1.0f + __expf(-x)); }

// Vt swizzle: 8-elem j-block index for (d, jblk). Involution; spreads banks on
// writes (d>>4) AND reads (d&7).
__device__ __forceinline__ int vswz(int jblk, int d) {
  return (jblk ^ (d & 7) ^ ((d >> 4) & 7)) << 3;
}

__global__ __launch_bounds__(NTH, 1)
void cpka(const float* __restrict__ q, const float* __restrict__ k,
          const float* __restrict__ v, float* __restrict__ outp,
          float* __restrict__ attnp) {
  // XCD-chunked swizzle: 1024 blocks = 8 XCDs x 128; same-bh blocks share an XCD L2.
  const int hw = blockIdx.x;
  const int lg = (hw & 7) * 128 + (hw >> 3);
  const int bh = lg >> 4;
  const int i0 = (lg & 15) * IT;
  const int t = threadIdx.x;
  const int lane = t & 63;
  const int w = t >> 6;                 // wave 0..15
  const int l15 = lane & 15, l4 = lane >> 4;
  const int wjf = w & 3;                // j-frag 0..3 (16 cols)
  const int wip = w >> 2;               // i-frag 0..3 (16 rows)

  __shared__ unsigned short Qhi[IT * SI];   // q-hat i-rows
  __shared__ unsigned short Kii[IT * SI];   // raw K i-rows
  __shared__ unsigned short Sqi[IT * SI];   // sigmoid(q-hat) i-rows
  __shared__ unsigned short Khj[JT * SJ];   // k-hat j-rows
  __shared__ unsigned short Qjj[JT * SJ];   // raw Q j-rows
  __shared__ unsigned short Skj[JT * SJ];   // sigmoid(k-hat) j-rows
  __shared__ unsigned short Vt[kD * 64];    // V^T tile [d][j], swizzled 8-elem blocks
  __shared__ unsigned short PreT[IT * SPT]; // per-tile unnormalized pre, bf16
  __shared__ float s_qn2i[IT], s_kn2i[IT], s_sqsi[IT];
  __shared__ float s_qn2j[JT], s_kn2j[JT], s_sksj[JT];
  __shared__ float s_part[4][IT];
  __shared__ float s_invn[IT];

  const float* qb = q + (size_t)bh * kN * kD;
  const float* kb = k + (size_t)bh * kN * kD;
  const float* vb = v + (size_t)bh * kN * kD;
  float* attb = attnp + (size_t)bh * kN * kN;
  float* outb = outp + (size_t)bh * kN * kD;

  // ---------------- i-side staging (once): 8 threads/row, 16 f32 each ----------------
  {
    const bool isQ = (t < 512);
    const int tt = isQ ? t : t - 512;
    const int row = tt >> 3, qt = tt & 7;
    const float* src = (isQ ? qb : kb) + (size_t)(i0 + row) * kD + qt * 16;
    float4 vv[4];
    float ss = 0.f;
#pragma unroll
    for (int c = 0; c < 4; ++c) {
      vv[c] = ((const float4*)src)[c];
      ss += vv[c].x * vv[c].x + vv[c].y * vv[c].y + vv[c].z * vv[c].z + vv[c].w * vv[c].w;
    }
    ss += __shfl_xor(ss, 1);
    ss += __shfl_xor(ss, 2);
    ss += __shfl_xor(ss, 4);
    if (isQ) {
      const float rn = rsqrtf(ss);
      float sg = 0.f;
#pragma unroll
      for (int c = 0; c < 4; ++c) {
        float x0 = vv[c].x * rn, x1 = vv[c].y * rn, x2 = vv[c].z * rn, x3 = vv[c].w * rn;
        s16x4 hb; hb[0] = f2bf(x0); hb[1] = f2bf(x1); hb[2] = f2bf(x2); hb[3] = f2bf(x3);
        *(s16x4*)&Qhi[row * SI + qt * 16 + c * 4] = hb;
        float g0 = sigm(x0), g1 = sigm(x1), g2 = sigm(x2), g3 = sigm(x3);
        sg += g0 + g1 + g2 + g3;
        s16x4 sb; sb[0] = f2bf(g0); sb[1] = f2bf(g1); sb[2] = f2bf(g2); sb[3] = f2bf(g3);
        *(s16x4*)&Sqi[row * SI + qt * 16 + c * 4] = sb;
      }
      sg += __shfl_xor(sg, 1);
      sg += __shfl_xor(sg, 2);
      sg += __shfl_xor(sg, 4);
      if (qt == 0) { s_qn2i[row] = ss; s_sqsi[row] = sg; }
    } else {
#pragma unroll
      for (int c = 0; c < 4; ++c) {
        s16x4 hb;
        hb[0] = f2bf(vv[c].x); hb[1] = f2bf(vv[c].y);
        hb[2] = f2bf(vv[c].z); hb[3] = f2bf(vv[c].w);
        *(s16x4*)&Kii[row * SI + qt * 16 + c * 4] = hb;
      }
      if (qt == 0) s_kn2i[row] = ss;
    }
  }

  f32x4 oacc[2];
#pragma unroll
  for (int np = 0; np < 2; ++np) oacc[np] = (f32x4){0.f, 0.f, 0.f, 0.f};
  float rowss = 0.f;

  for (int jt = 0; jt < kN / JT; ++jt) {
    const int j0 = jt * JT;
    __syncthreads();   // prev tile's PV/attn readers done before restage

    // ---------------- j-side staging: 8 threads/row, 16 f32 each ----------------
    if (t < 512) {          // K rows: khat, sigm(khat), kn2, sks
      const int row = t >> 3, qt = t & 7;
      const float* src = kb + (size_t)(j0 + row) * kD + qt * 16;
      float4 vv[4];
      float ss = 0.f;
#pragma unroll
      for (int c = 0; c < 4; ++c) {
        vv[c] = ((const float4*)src)[c];
        ss += vv[c].x * vv[c].x + vv[c].y * vv[c].y + vv[c].z * vv[c].z + vv[c].w * vv[c].w;
      }
      ss += __shfl_xor(ss, 1);
      ss += __shfl_xor(ss, 2);
      ss += __shfl_xor(ss, 4);
      const float rn = rsqrtf(ss);
      float sg = 0.f;
#pragma unroll
      for (int c = 0; c < 4; ++c) {
        float x0 = vv[c].x * rn, x1 = vv[c].y * rn, x2 = vv[c].z * rn, x3 = vv[c].w * rn;
        s16x4 hb; hb[0] = f2bf(x0); hb[1] = f2bf(x1); hb[2] = f2bf(x2); hb[3] = f2bf(x3);
        *(s16x4*)&Khj[row * SJ + qt * 16 + c * 4] = hb;
        float g0 = sigm(x0), g1 = sigm(x1), g2 = sigm(x2), g3 = sigm(x3);
        sg += g0 + g1 + g2 + g3;
        s16x4 sb; sb[0] = f2bf(g0); sb[1] = f2bf(g1); sb[2] = f2bf(g2); sb[3] = f2bf(g3);
        *(s16x4*)&Skj[row * SJ + qt * 16 + c * 4] = sb;
      }
      sg += __shfl_xor(sg, 1);
      sg += __shfl_xor(sg, 2);
      sg += __shfl_xor(sg, 4);
      if (qt == 0) { s_kn2j[row] = ss; s_sksj[row] = sg; }
    } else {                // Q rows: raw bf16 + qn2
      const int tt = t - 512;
      const int row = tt >> 3, qt = tt & 7;
      const float* src = qb + (size_t)(j0 + row) * kD + qt * 16;
      float ss = 0.f;
#pragma unroll
      for (int c = 0; c < 4; ++c) {
        float4 vv = ((const float4*)src)[c];
        ss += vv.x * vv.x + vv.y * vv.y + vv.z * vv.z + vv.w * vv.w;
        s16x4 hb;
        hb[0] = f2bf(vv.x); hb[1] = f2bf(vv.y); hb[2] = f2bf(vv.z); hb[3] = f2bf(vv.w);
        *(s16x4*)&Qjj[row * SJ + qt * 16 + c * 4] = hb;
      }
      ss += __shfl_xor(ss, 1);
      ss += __shfl_xor(ss, 2);
      ss += __shfl_xor(ss, 4);
      if (qt == 0) s_qn2j[row] = ss;
    }
    {  // V tile -> transposed [d][j], swizzled; 16 threads/row, 8 d each
      const int row = t >> 4, qt = t & 15;
      const float* src = vb + (size_t)(j0 + row) * kD + qt * 8;
      const int jblk = row >> 3, jlow = row & 7;
#pragma unroll
      for (int c = 0; c < 2; ++c) {
        float4 vv = ((const float4*)src)[c];
        const int d0 = qt * 8 + c * 4;
        Vt[(d0 + 0) * 64 + vswz(jblk, d0 + 0) + jlow] = f2bf(vv.x);
        Vt[(d0 + 1) * 64 + vswz(jblk, d0 + 1) + jlow] = f2bf(vv.y);
        Vt[(d0 + 2) * 64 + vswz(jblk, d0 + 2) + jlow] = f2bf(vv.z);
        Vt[(d0 + 3) * 64 + vswz(jblk, d0 + 3) + jlow] = f2bf(vv.w);
      }
    }
    __syncthreads();

    // ---------------- grams (P^T: a = j-side, b = i-side) ----------------
    f32x4 acos = (f32x4){0.f, 0.f, 0.f, 0.f};
    f32x4 ase  = (f32x4){0.f, 0.f, 0.f, 0.f};
    f32x4 as1  = (f32x4){0.f, 0.f, 0.f, 0.f};
    const int arow = (wjf * 16 + l15) * SJ + l4 * 8;
    const int brow = (wip * 16 + l15) * SI + l4 * 8;
#pragma unroll
    for (int ks = 0; ks < 4; ++ks) {
      const int ao = arow + ks * 32;
      const int bo = brow + ks * 32;
      acos = __builtin_amdgcn_mfma_f32_16x16x32_bf16(
          *(const s16x8*)&Khj[ao], *(const s16x8*)&Qhi[bo], acos, 0, 0, 0);
      ase  = __builtin_amdgcn_mfma_f32_16x16x32_bf16(
          *(const s16x8*)&Qjj[ao], *(const s16x8*)&Kii[bo], ase, 0, 0, 0);
      as1  = __builtin_amdgcn_mfma_f32_16x16x32_bf16(
          *(const s16x8*)&Skj[ao], *(const s16x8*)&Sqi[bo], as1, 0, 0, 0);
    }

    // ---------------- epilogue: pre, row-sumsq, pack to PreT ----------------
    {
      const int iloc = wip * 16 + l15;
      const float kn2i = s_kn2i[iloc], qn2i = s_qn2i[iloc], sqsi = s_sqsi[iloc];
      s16x4 pk;
#pragma unroll
      for (int r = 0; r < 4; ++r) {
        const int jloc = wjf * 16 + l4 * 4 + r;
        const float kq = ase[r];    // q_j . k_i (index-crossed SE term)
        const float cs = acos[r];   // qhat_i . khat_j
        const float s1 = as1[r];    // sig(qhat_i) . sig(khat_j)
        const float se = -sqrtf(fmaxf(kn2i + s_qn2j[jloc] - 2.0f * kq, 0.f)) * INV2SD;
        // -2 sin^2(pi*sqrt(X)) = cos(2*pi*sqrt(X)) - 1; v_cos takes revolutions = sqrt(X)
        const float rev = sqrtf(fmaxf(TWOA - 2.0f * cs, 0.f));
        const float per = (__builtin_amdgcn_cosf(rev) - 1.0f) * INVSD;
        const float Bc = 128.0f - sqsi - s_sksj[jloc] + s1;
        const float p = s1 * __expf(se) + Bc * __expf(per)
                        + (qn2i + s_kn2j[jloc]) * INV2SD;
        rowss += p * p;
        pk[r] = (short)f2bf(p);
      }
      *(s16x4*)&PreT[iloc * SPT + wjf * 16 + l4 * 4] = pk;
    }
    __syncthreads();

    // ---------------- attn tile: unnormalized, coalesced ----------------
    {
      const int row = t >> 4, col = (t & 15) * 4;
      const s16x4 hv = *(const s16x4*)&PreT[row * SPT + col];
      f32x4 w0;
      w0[0] = bf2f((unsigned short)hv[0]); w0[1] = bf2f((unsigned short)hv[1]);
      w0[2] = bf2f((unsigned short)hv[2]); w0[3] = bf2f((unsigned short)hv[3]);
      *(f32x4*)(attb + (size_t)(i0 + row) * kN + j0 + col) = w0;
    }

    // ---------------- PV: out += P_tile @ V_tile ----------------
#pragma unroll
    for (int ks2 = 0; ks2 < 2; ++ks2) {
      const s16x8 A = *(const s16x8*)&PreT[(wip * 16 + l15) * SPT + ks2 * 32 + l4 * 8];
#pragma unroll
      for (int np = 0; np < 2; ++np) {
        const int d = wjf * 32 + np * 16 + l15;
        const s16x8 B = *(const s16x8*)&Vt[d * 64 + vswz(ks2 * 4 + l4, d)];
        oacc[np] = __builtin_amdgcn_mfma_f32_16x16x32_bf16(A, B, oacc[np], 0, 0, 0);
      }
    }
  }  // jt

  // ---------------- row L2 norm (for out; attn rescaled in pass 2) ----------------
  {
    float rsv = rowss;
    rsv += __shfl_xor(rsv, 16);
    rsv += __shfl_xor(rsv, 32);
    if (l4 == 0) s_part[wjf][wip * 16 + l15] = rsv;
  }
  __syncthreads();
  if (t < IT) {
    const float ssum = s_part[0][t] + s_part[1][t] + s_part[2][t] + s_part[3][t];
    s_invn[t] = 1.0f / fmaxf(sqrtf(ssum), 1e-12f);
  }
  __syncthreads();

  // ---------------- out = (pre @ vals) * invn ----------------
#pragma unroll
  for (int np = 0; np < 2; ++np)
#pragma unroll
    for (int r = 0; r < 4; ++r) {
      const int iloc = wip * 16 + l4 * 4 + r;
      const int d = wjf * 32 + np * 16 + l15;
      outb[(size_t)(i0 + iloc) * kD + d] = oacc[np][r] * s_invn[iloc];
    }
}

// Pass 2: L2-normalize each attn row in place (recomputes denom from the
// unnormalized f32 row it reads anyway -- zero extra traffic, no ws needed).
__global__ __launch_bounds__(256, 8)
void cpka_rescale(float* __restrict__ attnp) {
  const size_t row = (size_t)blockIdx.x * 4 + (threadIdx.x >> 6);
  const int lane = threadIdx.x & 63;
  f32x4* rp = (f32x4*)(attnp + row * kN);
  f32x4 x[4];
  float ss = 0.f;
#pragma unroll
  for (int u = 0; u < 4; ++u) {
    x[u] = rp[lane + u * 64];
    ss += x[u][0] * x[u][0] + x[u][1] * x[u][1] + x[u][2] * x[u][2] + x[u][3] * x[u][3];
  }
#pragma unroll
  for (int m = 1; m < 64; m <<= 1) ss += __shfl_xor(ss, m);
  const float inv = 1.0f / fmaxf(sqrtf(ss), 1e-12f);
#pragma unroll
  for (int u = 0; u < 4; ++u) {
    f32x4 y = x[u];
    y[0] *= inv; y[1] *= inv; y[2] *= inv; y[3] *= inv;
    __builtin_nontemporal_store(y, &rp[lane + u * 64]);
  }
}

}  // namespace

extern "C" void kernel_launch(void* const* d_in, const int* in_sizes, int n_in,
                              void* d_out, int out_size, void* d_ws, size_t ws_size,
                              hipStream_t stream) {
  (void)in_sizes; (void)n_in; (void)out_size; (void)d_ws; (void)ws_size;
  const float* q = (const float*)d_in[0];
  const float* k = (const float*)d_in[1];
  const float* v = (const float*)d_in[2];
  float* outp = (float*)d_out;
  float* attnp = outp + (size_t)kBH * kN * kD;
  dim3 grid(kBH * (kN / IT));   // 1024 = 8 XCDs * 128
  cpka<<<grid, NTH, 0, stream>>>(q, k, v, outp, attnp);
  dim3 grid2(kBH * kN / 4);     // 4 rows per block
  cpka_rescale<<<grid2, 256, 0, stream>>>(attnp);
}